// Round 5
// baseline (23.004 us; speedup 1.0000x reference)
//
#include <hip/hip_runtime.h>
#include <math.h>

// pred/targ: f32 [B=4096, H=128, D=64]; out: scalar f32.
//
// per_sample[i] = (1 + 0.5*(t/(H-1))^2.5) * sum_d( diff^2 + |diff - prev_diff| )
//   at row idx = t-1 (H-1 if t==0), t = nnz(targ[i,:,1]),
//   diff = pred[i,idx,:]-targ[i,idx,:], prev_diff = row idx-1 (0 if idx==0).
// out = mean_i per_sample[i]
//
// R5: fully wave-local stage 1 (no LDS, no __syncthreads).
//   Each wave owns 2 samples. Per lane: 4 column loads (2 per sample cover
//   all 128 h) + 8 speculative row loads (rows 127/126, the t==128 common
//   case) -> 12 independent loads, ONE memory round-trip. t via 2 ballots +
//   popcount, all in-wave. Shuffle-reduce, lane 0 writes one per-wave
//   partial (pre-scaled by 1/B).
// Stage 2: single block reduces the 2048 per-wave partials (fixed order).
// Two dispatches on purpose: R2 showed per-block device-scope fences/atomics
// cost ~100ns serialized on CDNA4 (2048 of them -> 180us).

#define H_DIM 128
#define D_DIM 64

__global__ __launch_bounds__(256) void wsl_stage1(
    const float* __restrict__ pred,
    const float* __restrict__ targ,
    float* __restrict__ partials,        // [gridDim.x * 4] per-wave sums
    float invB)
{
    const int wave = threadIdx.x >> 6;                 // 0..3
    const int lane = threadIdx.x & 63;
    const int sA   = blockIdx.x * 8 + wave * 2;        // this wave's samples
    const int sB   = sA + 1;
    const long long baseA = (long long)sA * (H_DIM * D_DIM);
    const long long baseB = (long long)sB * (H_DIM * D_DIM);

    // ---- issue all 12 independent loads up front (one round-trip) ----
    // nnz columns: sample's h=lane and h=lane+64, element d=1
    const float cA0 = targ[baseA + (long long)lane * D_DIM + 1];
    const float cA1 = targ[baseA + (long long)(lane + 64) * D_DIM + 1];
    const float cB0 = targ[baseB + (long long)lane * D_DIM + 1];
    const float cB1 = targ[baseB + (long long)(lane + 64) * D_DIM + 1];
    // speculative rows 127 / 126 (t==128 fast path), element d=lane
    const float pA_c = pred[baseA + 127 * D_DIM + lane];
    const float tA_c = targ[baseA + 127 * D_DIM + lane];
    const float pA_p = pred[baseA + 126 * D_DIM + lane];
    const float tA_p = targ[baseA + 126 * D_DIM + lane];
    const float pB_c = pred[baseB + 127 * D_DIM + lane];
    const float tB_c = targ[baseB + 127 * D_DIM + lane];
    const float pB_p = pred[baseB + 126 * D_DIM + lane];
    const float tB_p = targ[baseB + 126 * D_DIM + lane];

    // ---- t per sample, entirely wave-local ----
    const int tA = __popcll(__ballot(cA0 != 0.0f)) + __popcll(__ballot(cA1 != 0.0f));
    const int tB = __popcll(__ballot(cB0 != 0.0f)) + __popcll(__ballot(cB1 != 0.0f));

    // ---- per-sample row term (fast path: speculation hit) ----
    float dcurA, dprevA, dcurB, dprevB;
    if (tA == H_DIM) {
        dcurA = pA_c - tA_c;  dprevA = pA_p - tA_p;
    } else {
        int idx = tA - 1; if (idx < 0) idx = H_DIM - 1;   // torch neg-index mimic
        const long long off = baseA + (long long)idx * D_DIM + lane;
        dcurA = pred[off] - targ[off];
        dprevA = (idx >= 1) ? (pred[off - D_DIM] - targ[off - D_DIM]) : 0.0f;
    }
    if (tB == H_DIM) {
        dcurB = pB_c - tB_c;  dprevB = pB_p - tB_p;
    } else {
        int idx = tB - 1; if (idx < 0) idx = H_DIM - 1;
        const long long off = baseB + (long long)idx * D_DIM + lane;
        dcurB = pred[off] - targ[off];
        dprevB = (idx >= 1) ? (pred[off - D_DIM] - targ[off - D_DIM]) : 0.0f;
    }

    float sA_ = dcurA * dcurA + fabsf(dcurA - dprevA);
    float sB_ = dcurB * dcurB + fabsf(dcurB - dprevB);

    // ---- joint wave reduce of both sums ----
    #pragma unroll
    for (int sh = 32; sh >= 1; sh >>= 1) {
        sA_ += __shfl_down(sA_, sh, 64);
        sB_ += __shfl_down(sB_, sh, 64);
    }

    if (lane == 0) {
        const float fA = (float)tA / (float)(H_DIM - 1);
        const float fB = (float)tB / (float)(H_DIM - 1);
        const float wA = 1.0f + 0.5f * powf(fA, 2.5f);
        const float wB = 1.0f + 0.5f * powf(fB, 2.5f);
        partials[blockIdx.x * 4 + wave] = (wA * sA_ + wB * sB_) * invB;
    }
}

__global__ __launch_bounds__(256) void wsl_stage2(
    const float* __restrict__ partials,
    float* __restrict__ out,
    int n)                                // n = 2048
{
    __shared__ float s[256];
    const int tid = threadIdx.x;
    float acc = 0.0f;
    #pragma unroll
    for (int k = 0; k < 8; ++k) {         // fixed order -> deterministic
        const int j = tid + k * 256;
        if (j < n) acc += partials[j];
    }
    s[tid] = acc;
    __syncthreads();
    #pragma unroll
    for (int st = 128; st >= 1; st >>= 1) {
        if (tid < st) s[tid] += s[tid + st];
        __syncthreads();
    }
    if (tid == 0) out[0] = s[0];
}

extern "C" void kernel_launch(void* const* d_in, const int* in_sizes, int n_in,
                              void* d_out, int out_size, void* d_ws, size_t ws_size,
                              hipStream_t stream)
{
    const float* pred = (const float*)d_in[0];
    const float* targ = (const float*)d_in[1];
    float* out = (float*)d_out;

    const int B = in_sizes[0] / (H_DIM * D_DIM);   // 4096
    const int nblocks = B / 8;                     // 512
    const int npart = nblocks * 4;                 // 2048

    float* partials = (float*)d_ws;

    wsl_stage1<<<nblocks, 256, 0, stream>>>(pred, targ, partials, 1.0f / (float)B);
    wsl_stage2<<<1, 256, 0, stream>>>(partials, out, npart);
}

// Round 6
// 22.565 us; speedup vs baseline: 1.0195x; 1.0195x over previous
//
#include <hip/hip_runtime.h>
#include <math.h>

// pred/targ: f32 [B=4096, H=128, D=64]; out: scalar f32.
//
// per_sample[i] = (1 + 0.5*(t/(H-1))^2.5) * sum_d( diff^2 + |diff - prev_diff| )
//   at row idx = t-1 (H-1 if t==0), t = nnz(targ[i,:,1]),
//   diff = pred[i,idx,:]-targ[i,idx,:], prev_diff = row idx-1 (0 if idx==0).
// out = mean_i per_sample[i]
//
// R6: SINGLE dispatch. Cross-block handoff WITHOUT __threadfence (R2: agent
// release fence = buffer_wbl2 per block = 10x regression on CDNA4):
//   - per-wave partials written with atomicExch (device-scope RMW -> executes
//     at the shared coherence point / Infinity Cache; never resides in the
//     non-coherent per-XCD L2s)
//   - s_waitcnt vmcnt(0) + __syncthreads proves the block's 4 partials have
//     COMPLETED at IC before the block's single ticket atomicAdd
//   - ticket never reset: last block = (rank & (nblocks-1)) == nblocks-1;
//     2^32 % 512 == 0 so the modulo stays consistent across graph replays
//     (and any 0xAA poison start value). Exactly one last block per launch.
//   - last block reads partials with agent-scope relaxed loads (bypass L1/L2,
//     served by IC) and reduces in FIXED order -> deterministic output.

#define H_DIM 128
#define D_DIM 64

__global__ __launch_bounds__(256) void wsl_onepass(
    const float* __restrict__ pred,
    const float* __restrict__ targ,
    float* __restrict__ partials,        // [nblocks*4]; only atomic access ever
    unsigned int* __restrict__ ticket,   // [1]; monotonic across replays
    float* __restrict__ out,
    float invB, int nblocks)
{
    const int tid  = threadIdx.x;
    const int wave = tid >> 6;
    const int lane = tid & 63;
    const int sA   = blockIdx.x * 8 + wave * 2;        // this wave's 2 samples
    const int sB   = sA + 1;
    const long long baseA = (long long)sA * (H_DIM * D_DIM);
    const long long baseB = (long long)sB * (H_DIM * D_DIM);

    __shared__ unsigned int s_last;
    __shared__ float sred[256];

    // ---- 12 independent loads up front (one memory round-trip) ----
    // nnz columns (h = lane, lane+64; d = 1)
    const float cA0 = targ[baseA + (long long)lane * D_DIM + 1];
    const float cA1 = targ[baseA + (long long)(lane + 64) * D_DIM + 1];
    const float cB0 = targ[baseB + (long long)lane * D_DIM + 1];
    const float cB1 = targ[baseB + (long long)(lane + 64) * D_DIM + 1];
    // speculative rows 127/126 (t==128 fast path; address-independent of cols)
    const float pA_c = pred[baseA + 127 * D_DIM + lane];
    const float tA_c = targ[baseA + 127 * D_DIM + lane];
    const float pA_p = pred[baseA + 126 * D_DIM + lane];
    const float tA_p = targ[baseA + 126 * D_DIM + lane];
    const float pB_c = pred[baseB + 127 * D_DIM + lane];
    const float tB_c = targ[baseB + 127 * D_DIM + lane];
    const float pB_p = pred[baseB + 126 * D_DIM + lane];
    const float tB_p = targ[baseB + 126 * D_DIM + lane];

    // ---- t per sample, wave-local ----
    const int tA = __popcll(__ballot(cA0 != 0.0f)) + __popcll(__ballot(cA1 != 0.0f));
    const int tB = __popcll(__ballot(cB0 != 0.0f)) + __popcll(__ballot(cB1 != 0.0f));

    // ---- per-sample row term ----
    float dcurA, dprevA, dcurB, dprevB;
    if (tA == H_DIM) {
        dcurA = pA_c - tA_c;  dprevA = pA_p - tA_p;
    } else {
        int idx = tA - 1; if (idx < 0) idx = H_DIM - 1;   // torch neg-index mimic
        const long long off = baseA + (long long)idx * D_DIM + lane;
        dcurA = pred[off] - targ[off];
        dprevA = (idx >= 1) ? (pred[off - D_DIM] - targ[off - D_DIM]) : 0.0f;
    }
    if (tB == H_DIM) {
        dcurB = pB_c - tB_c;  dprevB = pB_p - tB_p;
    } else {
        int idx = tB - 1; if (idx < 0) idx = H_DIM - 1;
        const long long off = baseB + (long long)idx * D_DIM + lane;
        dcurB = pred[off] - targ[off];
        dprevB = (idx >= 1) ? (pred[off - D_DIM] - targ[off - D_DIM]) : 0.0f;
    }

    float sA_ = dcurA * dcurA + fabsf(dcurA - dprevA);
    float sB_ = dcurB * dcurB + fabsf(dcurB - dprevB);

    #pragma unroll
    for (int sh = 32; sh >= 1; sh >>= 1) {
        sA_ += __shfl_down(sA_, sh, 64);
        sB_ += __shfl_down(sB_, sh, 64);
    }

    if (lane == 0) {
        const float fA = (float)tA / (float)(H_DIM - 1);
        const float fB = (float)tB / (float)(H_DIM - 1);
        const float wA = 1.0f + 0.5f * powf(fA, 2.5f);
        const float wB = 1.0f + 0.5f * powf(fB, 2.5f);
        const float pv = (wA * sA_ + wB * sB_) * invB;
        // device-scope RMW: lands at the shared coherence point (IC),
        // never in a non-coherent per-XCD L2
        atomicExch(&partials[blockIdx.x * 4 + wave], pv);
    }
    // completion ordering instead of a release fence (no buffer_wbl2):
    asm volatile("s_waitcnt vmcnt(0)" ::: "memory");  // this wave's exch done
    __syncthreads();                                  // => all 4 partials at IC

    if (tid == 0) {
        const unsigned int rank = atomicAdd(ticket, 1u);  // device-scope RMW
        s_last = ((rank & (unsigned)(nblocks - 1)) == (unsigned)(nblocks - 1)) ? 1u : 0u;
    }
    __syncthreads();

    if (s_last) {
        const int n = nblocks * 4;
        float acc = 0.0f;
        for (int j = tid; j < n; j += 256) {              // fixed order
            acc += __hip_atomic_load(&partials[j], __ATOMIC_RELAXED,
                                     __HIP_MEMORY_SCOPE_AGENT);
        }
        sred[tid] = acc;
        __syncthreads();
        #pragma unroll
        for (int st = 128; st >= 1; st >>= 1) {
            if (tid < st) sred[tid] += sred[tid + st];
            __syncthreads();
        }
        if (tid == 0) out[0] = sred[0];
    }
}

extern "C" void kernel_launch(void* const* d_in, const int* in_sizes, int n_in,
                              void* d_out, int out_size, void* d_ws, size_t ws_size,
                              hipStream_t stream)
{
    const float* pred = (const float*)d_in[0];
    const float* targ = (const float*)d_in[1];
    float* out = (float*)d_out;

    const int B = in_sizes[0] / (H_DIM * D_DIM);   // 4096
    const int nblocks = B / 8;                     // 512 (power of two)

    float* partials      = (float*)d_ws;                       // nblocks*4 floats
    unsigned int* ticket = (unsigned int*)(partials + nblocks * 4);

    wsl_onepass<<<nblocks, 256, 0, stream>>>(
        pred, targ, partials, ticket, out, 1.0f / (float)B, nblocks);
}